// Round 1
// baseline (1008.182 us; speedup 1.0000x reference)
//
#include <hip/hip_runtime.h>
#include <math.h>

// Problem constants (from reference): N=50000, E=800000, IN=256, H=4, F=64.
constexpr float SLOPE = 0.2f;

// ---------------------------------------------------------------------------
// GEMM: C = x @ B  with x [M,256] f32, B [256,256] f32, C [M,256] f32.
// blockIdx.z selects (W -> proj) or (skip_w -> out).
// 64x64 tile, K-tile 16, 256 threads, 4x4 acc per thread. Classic f32 tiling.
// ---------------------------------------------------------------------------
__global__ __launch_bounds__(256) void gemm64(
    const float* __restrict__ x,
    const float* __restrict__ B0, const float* __restrict__ B1,
    float* __restrict__ C0, float* __restrict__ C1, int M)
{
    const float* __restrict__ B = blockIdx.z ? B1 : B0;
    float* __restrict__ C       = blockIdx.z ? C1 : C0;

    __shared__ float As[64][16];
    __shared__ float Bs[16][64];

    const int row0 = blockIdx.x * 64;
    const int col0 = blockIdx.y * 64;
    const int t  = threadIdx.x;      // 0..255
    const int tx = t & 15;           // 0..15 (col group)
    const int ty = t >> 4;           // 0..15 (row group)

    // staging indices
    const int ar = t >> 2;           // 0..63  row within A tile
    const int ak = (t & 3) * 4;      // 0,4,8,12
    const int bk = t >> 4;           // 0..15  k within B tile
    const int bc = (t & 15) * 4;     // 0..60

    float acc[4][4] = {};

    for (int k0 = 0; k0 < 256; k0 += 16) {
        const int gr = row0 + ar;
        float4 av;
        if (gr < M) av = *(const float4*)(x + (size_t)gr * 256 + k0 + ak);
        else        av = make_float4(0.f, 0.f, 0.f, 0.f);
        *(float4*)(&As[ar][ak]) = av;

        float4 bv = *(const float4*)(B + (size_t)(k0 + bk) * 256 + col0 + bc);
        *(float4*)(&Bs[bk][bc]) = bv;

        __syncthreads();

#pragma unroll
        for (int kk = 0; kk < 16; ++kk) {
            float4 b = *(const float4*)(&Bs[kk][tx * 4]);
#pragma unroll
            for (int i = 0; i < 4; ++i) {
                float a = As[ty * 4 + i][kk];
                acc[i][0] += a * b.x;
                acc[i][1] += a * b.y;
                acc[i][2] += a * b.z;
                acc[i][3] += a * b.w;
            }
        }
        __syncthreads();
    }

#pragma unroll
    for (int i = 0; i < 4; ++i) {
        const int gr = row0 + ty * 4 + i;
        if (gr < M) {
            float4 v = make_float4(acc[i][0], acc[i][1], acc[i][2], acc[i][3]);
            *(float4*)(C + (size_t)gr * 256 + col0 + tx * 4) = v;
        }
    }
}

// ---------------------------------------------------------------------------
// Per-node attention scores: s_src[n,h] = dot(proj[n,h,:], a_src[h,:]),
// same for s_trg. One block (4 waves) per node; wave h reduces 64 lanes.
// ---------------------------------------------------------------------------
__global__ __launch_bounds__(256) void scores_k(
    const float* __restrict__ proj,
    const float* __restrict__ a_src, const float* __restrict__ a_trg,
    float* __restrict__ s_src, float* __restrict__ s_trg)
{
    const int n = blockIdx.x;
    const int t = threadIdx.x;
    const int h = t >> 6;
    const int f = t & 63;

    float p  = proj[(size_t)n * 256 + t];
    float vs = p * a_src[h * 64 + f];
    float vt = p * a_trg[h * 64 + f];

#pragma unroll
    for (int off = 32; off > 0; off >>= 1) {
        vs += __shfl_down(vs, off);
        vt += __shfl_down(vt, off);
    }
    if (f == 0) {
        s_src[n * 4 + h] = vs;
        s_trg[n * 4 + h] = vt;
    }
}

// ---------------------------------------------------------------------------
// Edge pass 1: ex[e,h] = exp(leaky(s_src[src]+s_trg[trg])); denom += ex.
// Global-max subtraction of the reference cancels in attn = ex/denom
// (e <= ~6 so exp is safe in f32); the +1e-16 epsilon is negligible either way.
// ---------------------------------------------------------------------------
__global__ __launch_bounds__(256) void edge_scores(
    const int* __restrict__ esrc, const int* __restrict__ etrg,
    const float* __restrict__ s_src, const float* __restrict__ s_trg,
    float* __restrict__ exbuf, float* __restrict__ denom, int E)
{
    const int i = blockIdx.x * 256 + threadIdx.x;
    if (i >= E * 4) return;
    const int e = i >> 2, h = i & 3;
    const int s  = esrc[e];
    const int tg = etrg[e];
    float v = s_src[s * 4 + h] + s_trg[tg * 4 + h];
    v = v > 0.f ? v : SLOPE * v;
    float ex = expf(v);
    exbuf[i] = ex;
    atomicAdd(&denom[tg * 4 + h], ex);
}

// ---------------------------------------------------------------------------
// Edge pass 2: out[trg, :] += attn[h] * proj[src, :].
// One block = 256 threads = full 4x64 feature row; 4 edges per block.
// out already contains the skip projection (written by gemm64, z=1).
// ---------------------------------------------------------------------------
__global__ __launch_bounds__(256) void aggregate(
    const int* __restrict__ esrc, const int* __restrict__ etrg,
    const float* __restrict__ exbuf, const float* __restrict__ denom,
    const float* __restrict__ proj, float* __restrict__ out, int E)
{
    const int t = threadIdx.x;
    const int h = t >> 6;
    const int e0 = blockIdx.x * 4;
    const int e1 = (e0 + 4 < E) ? e0 + 4 : E;
    for (int e = e0; e < e1; ++e) {
        const int s  = esrc[e];
        const int tg = etrg[e];
        float attn = exbuf[e * 4 + h] / (denom[tg * 4 + h] + 1e-16f);
        atomicAdd(&out[(size_t)tg * 256 + t], attn * proj[(size_t)s * 256 + t]);
    }
}

// ---------------------------------------------------------------------------
// Finalize: out = leaky(out + bias), in place.
// ---------------------------------------------------------------------------
__global__ __launch_bounds__(256) void finalize(
    float* __restrict__ out, const float* __restrict__ bias, int total)
{
    const int i = blockIdx.x * 256 + threadIdx.x;
    if (i < total) {
        float v = out[i] + bias[i & 255];
        out[i] = v > 0.f ? v : SLOPE * v;
    }
}

extern "C" void kernel_launch(void* const* d_in, const int* in_sizes, int n_in,
                              void* d_out, int out_size, void* d_ws, size_t ws_size,
                              hipStream_t stream)
{
    const float* x     = (const float*)d_in[0];
    const float* W     = (const float*)d_in[1];
    const float* a_src = (const float*)d_in[2];
    const float* a_trg = (const float*)d_in[3];
    const float* skw   = (const float*)d_in[4];
    const float* bias  = (const float*)d_in[5];
    const int*   esrc  = (const int*)d_in[6];
    const int*   etrg  = (const int*)d_in[7];

    const int N = in_sizes[0] / 256;   // 50000
    const int E = in_sizes[6];         // 800000
    float* out = (float*)d_out;

    // workspace layout (f32): proj[N*256] | s_src[N*4] | s_trg[N*4] | denom[N*4] | ex[E*4]
    float* proj  = (float*)d_ws;
    float* s_src = proj  + (size_t)N * 256;
    float* s_trg = s_src + (size_t)N * 4;
    float* denom = s_trg + (size_t)N * 4;
    float* exbuf = denom + (size_t)N * 4;

    hipMemsetAsync(denom, 0, (size_t)N * 4 * sizeof(float), stream);

    dim3 g((N + 63) / 64, 256 / 64, 2);
    gemm64<<<g, 256, 0, stream>>>(x, W, skw, proj, out, N);

    scores_k<<<N, 256, 0, stream>>>(proj, a_src, a_trg, s_src, s_trg);

    edge_scores<<<(E * 4 + 255) / 256, 256, 0, stream>>>(esrc, etrg, s_src, s_trg,
                                                         exbuf, denom, E);

    aggregate<<<(E + 3) / 4, 256, 0, stream>>>(esrc, etrg, exbuf, denom, proj, out, E);

    finalize<<<(N * 256 + 255) / 256, 256, 0, stream>>>(out, bias, N * 256);
}

// Round 2
// 632.296 us; speedup vs baseline: 1.5945x; 1.5945x over previous
//
#include <hip/hip_runtime.h>
#include <math.h>

// Problem constants (from reference): N=50000, E=800000, IN=256, H=4, F=64.
constexpr float SLOPE = 0.2f;

// ---------------------------------------------------------------------------
// GEMM: C = x @ B  with x [M,256] f32, B [256,256] f32, C [M,256] f32.
// blockIdx.z selects (W -> proj) or (skip_w -> out).
// 64x64 tile, K-tile 16, 256 threads, 4x4 acc per thread. Classic f32 tiling.
// ---------------------------------------------------------------------------
__global__ __launch_bounds__(256) void gemm64(
    const float* __restrict__ x,
    const float* __restrict__ B0, const float* __restrict__ B1,
    float* __restrict__ C0, float* __restrict__ C1, int M)
{
    const float* __restrict__ B = blockIdx.z ? B1 : B0;
    float* __restrict__ C       = blockIdx.z ? C1 : C0;

    __shared__ float As[64][16];
    __shared__ float Bs[16][64];

    const int row0 = blockIdx.x * 64;
    const int col0 = blockIdx.y * 64;
    const int t  = threadIdx.x;      // 0..255
    const int tx = t & 15;           // 0..15 (col group)
    const int ty = t >> 4;           // 0..15 (row group)

    const int ar = t >> 2;           // 0..63  row within A tile
    const int ak = (t & 3) * 4;      // 0,4,8,12
    const int bk = t >> 4;           // 0..15  k within B tile
    const int bc = (t & 15) * 4;     // 0..60

    float acc[4][4] = {};

    for (int k0 = 0; k0 < 256; k0 += 16) {
        const int gr = row0 + ar;
        float4 av;
        if (gr < M) av = *(const float4*)(x + (size_t)gr * 256 + k0 + ak);
        else        av = make_float4(0.f, 0.f, 0.f, 0.f);
        *(float4*)(&As[ar][ak]) = av;

        float4 bv = *(const float4*)(B + (size_t)(k0 + bk) * 256 + col0 + bc);
        *(float4*)(&Bs[bk][bc]) = bv;

        __syncthreads();

#pragma unroll
        for (int kk = 0; kk < 16; ++kk) {
            float4 b = *(const float4*)(&Bs[kk][tx * 4]);
#pragma unroll
            for (int i = 0; i < 4; ++i) {
                float a = As[ty * 4 + i][kk];
                acc[i][0] += a * b.x;
                acc[i][1] += a * b.y;
                acc[i][2] += a * b.z;
                acc[i][3] += a * b.w;
            }
        }
        __syncthreads();
    }

#pragma unroll
    for (int i = 0; i < 4; ++i) {
        const int gr = row0 + ty * 4 + i;
        if (gr < M) {
            float4 v = make_float4(acc[i][0], acc[i][1], acc[i][2], acc[i][3]);
            *(float4*)(C + (size_t)gr * 256 + col0 + tx * 4) = v;
        }
    }
}

// ---------------------------------------------------------------------------
// Per-node attention scores: s_src[n,h] = dot(proj[n,h,:], a_src[h,:]).
// One block (4 waves) per node; wave h reduces its 64 lanes.
// ---------------------------------------------------------------------------
__global__ __launch_bounds__(256) void scores_k(
    const float* __restrict__ proj,
    const float* __restrict__ a_src, const float* __restrict__ a_trg,
    float* __restrict__ s_src, float* __restrict__ s_trg)
{
    const int n = blockIdx.x;
    const int t = threadIdx.x;
    const int h = t >> 6;
    const int f = t & 63;

    float p  = proj[(size_t)n * 256 + t];
    float vs = p * a_src[h * 64 + f];
    float vt = p * a_trg[h * 64 + f];

#pragma unroll
    for (int off = 32; off > 0; off >>= 1) {
        vs += __shfl_down(vs, off);
        vt += __shfl_down(vt, off);
    }
    if (f == 0) {
        s_src[n * 4 + h] = vs;
        s_trg[n * 4 + h] = vt;
    }
}

// ---------------------------------------------------------------------------
// CSR build step 1: histogram of target degrees.
// ---------------------------------------------------------------------------
__global__ __launch_bounds__(256) void hist_k(
    const int* __restrict__ etrg, int* __restrict__ cnt, int E)
{
    const int e = blockIdx.x * 256 + threadIdx.x;
    if (e < E) atomicAdd(&cnt[etrg[e]], 1);
}

// ---------------------------------------------------------------------------
// CSR build step 2: single-block exclusive scan (wave-shuffle based, only
// 2 barriers per 1024-chunk). Writes off[0..N] and a working copy cur[0..N).
// ---------------------------------------------------------------------------
__global__ __launch_bounds__(1024) void scan_k(
    const int* __restrict__ cnt, int* __restrict__ off, int* __restrict__ cur, int N)
{
    __shared__ int wsum[16];
    __shared__ int carry_s;
    const int t = threadIdx.x;
    const int lane = t & 63;
    const int w = t >> 6;
    if (t == 0) carry_s = 0;
    __syncthreads();

    for (int base = 0; base < N; base += 1024) {
        const int i = base + t;
        const int v = (i < N) ? cnt[i] : 0;
        // inclusive wave scan
        int s = v;
#pragma unroll
        for (int d = 1; d < 64; d <<= 1) {
            int o = __shfl_up(s, d);
            if (lane >= d) s += o;
        }
        if (lane == 63) wsum[w] = s;
        __syncthreads();
        // wave 0 scans the 16 wave totals
        if (w == 0 && lane < 16) {
            int ws = wsum[lane];
            int sc = ws;
#pragma unroll
            for (int d = 1; d < 16; d <<= 1) {
                int o = __shfl_up(sc, d);
                if (lane >= d) sc += o;
            }
            wsum[lane] = sc - ws;   // exclusive wave offset
        }
        __syncthreads();
        const int carry = carry_s;
        const int excl = carry + wsum[w] + s - v;
        if (i < N) { off[i] = excl; cur[i] = excl; }
        __syncthreads();
        if (t == 1023) carry_s = excl + v;   // running total
        __syncthreads();
    }
    if (t == 0) off[N] = carry_s;
}

// ---------------------------------------------------------------------------
// CSR build step 3: scatter edge sources into target-sorted order.
// ---------------------------------------------------------------------------
__global__ __launch_bounds__(256) void scatter_k(
    const int* __restrict__ esrc, const int* __restrict__ etrg,
    int* __restrict__ cur, int* __restrict__ srcs, int E)
{
    const int e = blockIdx.x * 256 + threadIdx.x;
    if (e < E) {
        const int pos = atomicAdd(&cur[etrg[e]], 1);
        srcs[pos] = esrc[e];
    }
}

// ---------------------------------------------------------------------------
// Fused softmax + aggregation + skip + bias + output activation.
// One block per target node; thread t owns feature element t (h=t>>6).
// attn = ex/denom cancels the reference's global-max shift, and the sum is
// linear, so accumulate unnormalized and divide once at the end.
// out already contains the skip projection (gemm64, z=1).
// ---------------------------------------------------------------------------
__global__ __launch_bounds__(256) void aggregate_csr(
    const int* __restrict__ off, const int* __restrict__ srcs,
    const float* __restrict__ s_src, const float* __restrict__ s_trg,
    const float* __restrict__ proj, const float* __restrict__ bias,
    float* __restrict__ out)
{
    const int n = blockIdx.x;
    const int t = threadIdx.x;
    const int h = t >> 6;

    const float st = s_trg[n * 4 + h];
    const int b0 = off[n], b1 = off[n + 1];

    float acc = 0.f, denom = 0.f;
    for (int i = b0; i < b1; ++i) {
        const int s = srcs[i];
        float v = s_src[s * 4 + h] + st;      // broadcast load (64 lanes same addr)
        v = v > 0.f ? v : SLOPE * v;
        const float ex = expf(v);
        denom += ex;
        acc += ex * proj[(size_t)s * 256 + t]; // coalesced 1 KB row gather
    }

    const size_t o = (size_t)n * 256 + t;
    float val = acc / (denom + 1e-16f) + out[o] + bias[t];
    out[o] = val > 0.f ? val : SLOPE * val;
}

extern "C" void kernel_launch(void* const* d_in, const int* in_sizes, int n_in,
                              void* d_out, int out_size, void* d_ws, size_t ws_size,
                              hipStream_t stream)
{
    const float* x     = (const float*)d_in[0];
    const float* W     = (const float*)d_in[1];
    const float* a_src = (const float*)d_in[2];
    const float* a_trg = (const float*)d_in[3];
    const float* skw   = (const float*)d_in[4];
    const float* bias  = (const float*)d_in[5];
    const int*   esrc  = (const int*)d_in[6];
    const int*   etrg  = (const int*)d_in[7];

    const int N = in_sizes[0] / 256;   // 50000
    const int E = in_sizes[6];         // 800000
    float* out = (float*)d_out;

    // workspace layout: proj[N*256] f32 | s_src[N*4] | s_trg[N*4] |
    //                   cnt[N] i32 | off[N+1] i32 | cur[N] i32 | srcs[E] i32
    float* proj  = (float*)d_ws;
    float* s_src = proj  + (size_t)N * 256;
    float* s_trg = s_src + (size_t)N * 4;
    int*   cnt   = (int*)(s_trg + (size_t)N * 4);
    int*   off   = cnt + N;
    int*   cur   = off + (N + 1);
    int*   srcs  = cur + N;

    hipMemsetAsync(cnt, 0, (size_t)N * sizeof(int), stream);

    dim3 g((N + 63) / 64, 256 / 64, 2);
    gemm64<<<g, 256, 0, stream>>>(x, W, skw, proj, out, N);

    scores_k<<<N, 256, 0, stream>>>(proj, a_src, a_trg, s_src, s_trg);

    hist_k<<<(E + 255) / 256, 256, 0, stream>>>(etrg, cnt, E);
    scan_k<<<1, 1024, 0, stream>>>(cnt, off, cur, N);
    scatter_k<<<(E + 255) / 256, 256, 0, stream>>>(esrc, etrg, cur, srcs, E);

    aggregate_csr<<<N, 256, 0, stream>>>(off, srcs, s_src, s_trg, proj, bias, out);
}

// Round 3
// 489.758 us; speedup vs baseline: 2.0585x; 1.2910x over previous
//
#include <hip/hip_runtime.h>
#include <math.h>

// Problem constants (from reference): N=50000, E=800000, IN=256, H=4, F=64.
constexpr float SLOPE = 0.2f;

typedef __bf16 bf16x8 __attribute__((ext_vector_type(8)));
typedef float  f32x4  __attribute__((ext_vector_type(4)));

__device__ __forceinline__ int imin(int a, int b) { return a < b ? a : b; }

// ---------------------------------------------------------------------------
// Weight prep: Bt[n][k] = bf16( n<256 ? W[k][n] : skw[k][n-256] ), n in [0,512).
// Tiny (131k elems) one-shot transpose+cast so GEMM B-staging is row-contig.
// ---------------------------------------------------------------------------
__global__ __launch_bounds__(256) void prep_w(
    const float* __restrict__ W, const float* __restrict__ skw,
    __bf16* __restrict__ Bt)
{
    const int i = blockIdx.x * 256 + threadIdx.x;   // i = n*256 + k
    const int n = i >> 8, k = i & 255;
    const float v = (n < 256) ? W[k * 256 + n] : skw[k * 256 + (n - 256)];
    Bt[i] = (__bf16)v;
}

// ---------------------------------------------------------------------------
// Fused MFMA GEMM: C[M,512] = bf16(x)[M,256] @ [W | skip_w].
// Cols 0..255 -> projb (bf16), cols 256..511 -> out (f32 skip values).
// 128x128 tile, BK=32, 4 waves; wave w owns rows w*32..w*32+31 (2x8 mfma tiles).
// mfma_f32_16x16x32_bf16: A[m=lane&15][k=quad*8+j], B[n=lane&15][k=quad*8+j],
// C/D: col=lane&15, row=quad*4+reg  (verified layouts, m89/m91).
// LDS rows padded to 40 bf16 (80 B): 2-way bank aliasing only (free).
// ---------------------------------------------------------------------------
__global__ __launch_bounds__(256) void gemm_mfma(
    const float* __restrict__ x, const __bf16* __restrict__ Bt,
    __bf16* __restrict__ projb, float* __restrict__ out, int M)
{
    __shared__ __bf16 As[128][40];
    __shared__ __bf16 Bs[128][40];

    const int t    = threadIdx.x;
    const int w    = t >> 6;
    const int lane = t & 63;
    const int q    = lane >> 4;
    const int ln   = lane & 15;

    const int row0 = blockIdx.x * 128;
    const int nblk = blockIdx.y;          // 0..3 -> global cols nblk*128..+127
    const int bt0  = nblk * 128;          // Bt row base (Bt row = global col)

    f32x4 acc[2][8] = {};

    for (int k0 = 0; k0 < 256; k0 += 32) {
        // ---- stage A (f32 -> bf16) and B: 2 passes x 256 threads x 16 B ----
#pragma unroll
        for (int p = 0; p < 2; ++p) {
            const int idx = p * 256 + t;
            const int r   = idx >> 2;          // 0..127
            const int ko  = (idx & 3) * 8;     // 0,8,16,24
            const int ga  = imin(row0 + r, M - 1);
            const float4 f0 = *(const float4*)(x + (size_t)ga * 256 + k0 + ko);
            const float4 f1 = *(const float4*)(x + (size_t)ga * 256 + k0 + ko + 4);
            bf16x8 av;
            av[0] = (__bf16)f0.x; av[1] = (__bf16)f0.y;
            av[2] = (__bf16)f0.z; av[3] = (__bf16)f0.w;
            av[4] = (__bf16)f1.x; av[5] = (__bf16)f1.y;
            av[6] = (__bf16)f1.z; av[7] = (__bf16)f1.w;
            *(bf16x8*)&As[r][ko] = av;
            *(bf16x8*)&Bs[r][ko] =
                *(const bf16x8*)(Bt + (size_t)(bt0 + r) * 256 + k0 + ko);
        }
        __syncthreads();

        bf16x8 af[2], bfr[8];
#pragma unroll
        for (int rb = 0; rb < 2; ++rb)
            af[rb] = *(const bf16x8*)&As[w * 32 + rb * 16 + ln][q * 8];
#pragma unroll
        for (int cb = 0; cb < 8; ++cb)
            bfr[cb] = *(const bf16x8*)&Bs[cb * 16 + ln][q * 8];
#pragma unroll
        for (int rb = 0; rb < 2; ++rb)
#pragma unroll
            for (int cb = 0; cb < 8; ++cb)
                acc[rb][cb] = __builtin_amdgcn_mfma_f32_16x16x32_bf16(
                    af[rb], bfr[cb], acc[rb][cb], 0, 0, 0);
        __syncthreads();
    }

    const bool isProj  = (nblk < 2);
    const int  colbase = (nblk & 1) * 128;
#pragma unroll
    for (int rb = 0; rb < 2; ++rb) {
#pragma unroll
        for (int r = 0; r < 4; ++r) {
            const int grow = row0 + w * 32 + rb * 16 + q * 4 + r;
            if (grow < M) {
#pragma unroll
                for (int cb = 0; cb < 8; ++cb) {
                    const float v = acc[rb][cb][r];
                    const int gcol = colbase + cb * 16 + ln;
                    if (isProj) projb[(size_t)grow * 256 + gcol] = (__bf16)v;
                    else        out[(size_t)grow * 256 + gcol]   = v;
                }
            }
        }
    }
}

// ---------------------------------------------------------------------------
// Per-node attention scores from bf16 proj: one block per node, wave h
// reduces its 64 lanes.
// ---------------------------------------------------------------------------
__global__ __launch_bounds__(256) void scores_k(
    const __bf16* __restrict__ projb,
    const float* __restrict__ a_src, const float* __restrict__ a_trg,
    float* __restrict__ s_src, float* __restrict__ s_trg)
{
    const int n = blockIdx.x;
    const int t = threadIdx.x;
    const int h = t >> 6;
    const int f = t & 63;

    const float p  = (float)projb[(size_t)n * 256 + t];
    float vs = p * a_src[h * 64 + f];
    float vt = p * a_trg[h * 64 + f];

#pragma unroll
    for (int off = 32; off > 0; off >>= 1) {
        vs += __shfl_down(vs, off);
        vt += __shfl_down(vt, off);
    }
    if (f == 0) {
        s_src[n * 4 + h] = vs;
        s_trg[n * 4 + h] = vt;
    }
}

// ---------------------------------------------------------------------------
// CSR build step 1: histogram of target degrees.
// ---------------------------------------------------------------------------
__global__ __launch_bounds__(256) void hist_k(
    const int* __restrict__ etrg, int* __restrict__ cnt, int E)
{
    const int e = blockIdx.x * 256 + threadIdx.x;
    if (e < E) atomicAdd(&cnt[etrg[e]], 1);
}

// ---------------------------------------------------------------------------
// CSR build step 2: single-block exclusive scan over degree counts.
// ---------------------------------------------------------------------------
__global__ __launch_bounds__(1024) void scan_k(
    const int* __restrict__ cnt, int* __restrict__ off, int* __restrict__ cur, int N)
{
    __shared__ int wsum[16];
    __shared__ int carry_s;
    const int t = threadIdx.x;
    const int lane = t & 63;
    const int w = t >> 6;
    if (t == 0) carry_s = 0;
    __syncthreads();

    for (int base = 0; base < N; base += 1024) {
        const int i = base + t;
        const int v = (i < N) ? cnt[i] : 0;
        int s = v;
#pragma unroll
        for (int d = 1; d < 64; d <<= 1) {
            int o = __shfl_up(s, d);
            if (lane >= d) s += o;
        }
        if (lane == 63) wsum[w] = s;
        __syncthreads();
        if (w == 0 && lane < 16) {
            int ws = wsum[lane];
            int sc = ws;
#pragma unroll
            for (int d = 1; d < 16; d <<= 1) {
                int o = __shfl_up(sc, d);
                if (lane >= d) sc += o;
            }
            wsum[lane] = sc - ws;   // exclusive wave offset
        }
        __syncthreads();
        const int carry = carry_s;
        const int excl = carry + wsum[w] + s - v;
        if (i < N) { off[i] = excl; cur[i] = excl; }
        __syncthreads();
        if (t == 1023) carry_s = excl + v;
        __syncthreads();
    }
    if (t == 0) off[N] = carry_s;
}

// ---------------------------------------------------------------------------
// CSR build step 3: scatter sources into target-sorted order AND precompute
// the per-(edge,head) exp weights (was recomputed 64x redundantly in the
// aggregate inner loop). Global-max shift of the reference cancels in
// ex/denom; scores are O(1-10) so f32 exp is safe.
// ---------------------------------------------------------------------------
__global__ __launch_bounds__(256) void scatter_k(
    const int* __restrict__ esrc, const int* __restrict__ etrg,
    int* __restrict__ cur,
    const float* __restrict__ s_src, const float* __restrict__ s_trg,
    int* __restrict__ srcs, float* __restrict__ exs, int E)
{
    const int e = blockIdx.x * 256 + threadIdx.x;
    if (e >= E) return;
    const int s  = esrc[e];
    const int tg = etrg[e];
    const int pos = atomicAdd(&cur[tg], 1);
    srcs[pos] = s;
    const float4 ss = *(const float4*)(s_src + (size_t)s * 4);
    const float4 st = *(const float4*)(s_trg + (size_t)tg * 4);
    float4 ex;
    float v;
    v = ss.x + st.x; v = v > 0.f ? v : SLOPE * v; ex.x = expf(v);
    v = ss.y + st.y; v = v > 0.f ? v : SLOPE * v; ex.y = expf(v);
    v = ss.z + st.z; v = v > 0.f ? v : SLOPE * v; ex.z = expf(v);
    v = ss.w + st.w; v = v > 0.f ? v : SLOPE * v; ex.w = expf(v);
    *(float4*)(exs + (size_t)pos * 4) = ex;
}

// ---------------------------------------------------------------------------
// Fused softmax + aggregation + skip + bias + output activation.
// One block per target node; thread t owns feature element t (h=t>>6).
// out already contains the skip projection (gemm_mfma cols 256..511).
// ---------------------------------------------------------------------------
__global__ __launch_bounds__(256) void aggregate_csr(
    const int* __restrict__ off, const int* __restrict__ srcs,
    const float* __restrict__ exs, const __bf16* __restrict__ projb,
    const float* __restrict__ bias, float* __restrict__ out)
{
    const int n = blockIdx.x;
    const int t = threadIdx.x;
    const int h = t >> 6;

    const int b0 = off[n], b1 = off[n + 1];

    float acc = 0.f, denom = 0.f;
    for (int i = b0; i < b1; ++i) {
        const int s   = srcs[i];                 // wave-broadcast load
        const float e = exs[(size_t)i * 4 + h];  // wave-broadcast load
        denom += e;
        acc += e * (float)projb[(size_t)s * 256 + t];  // coalesced 512 B row
    }

    const size_t o = (size_t)n * 256 + t;
    float val = acc / (denom + 1e-16f) + out[o] + bias[t];
    out[o] = val > 0.f ? val : SLOPE * val;
}

extern "C" void kernel_launch(void* const* d_in, const int* in_sizes, int n_in,
                              void* d_out, int out_size, void* d_ws, size_t ws_size,
                              hipStream_t stream)
{
    const float* x     = (const float*)d_in[0];
    const float* W     = (const float*)d_in[1];
    const float* a_src = (const float*)d_in[2];
    const float* a_trg = (const float*)d_in[3];
    const float* skw   = (const float*)d_in[4];
    const float* bias  = (const float*)d_in[5];
    const int*   esrc  = (const int*)d_in[6];
    const int*   etrg  = (const int*)d_in[7];

    const int N = in_sizes[0] / 256;   // 50000
    const int E = in_sizes[6];         // 800000
    float* out = (float*)d_out;

    // workspace: projb bf16[N*256] | Bt bf16[512*256] | s_src f32[N*4] |
    //            s_trg f32[N*4] | exs f32[E*4] | cnt,off,cur,srcs i32
    __bf16* projb = (__bf16*)d_ws;
    __bf16* Bt    = projb + (size_t)N * 256;
    float*  s_src = (float*)(Bt + 512 * 256);
    float*  s_trg = s_src + (size_t)N * 4;
    float*  exs   = s_trg + (size_t)N * 4;
    int*    cnt   = (int*)(exs + (size_t)E * 4);
    int*    off   = cnt + N;
    int*    cur   = off + (N + 1);
    int*    srcs  = cur + N;

    hipMemsetAsync(cnt, 0, (size_t)N * sizeof(int), stream);

    prep_w<<<512, 256, 0, stream>>>(W, skw, Bt);

    dim3 g((N + 127) / 128, 4);
    gemm_mfma<<<g, 256, 0, stream>>>(x, Bt, projb, out, N);

    scores_k<<<N, 256, 0, stream>>>(projb, a_src, a_trg, s_src, s_trg);

    hist_k<<<(E + 255) / 256, 256, 0, stream>>>(etrg, cnt, E);
    scan_k<<<1, 1024, 0, stream>>>(cnt, off, cur, N);
    scatter_k<<<(E + 255) / 256, 256, 0, stream>>>(esrc, etrg, cur, s_src, s_trg,
                                                   srcs, exs, E);

    aggregate_csr<<<N, 256, 0, stream>>>(off, srcs, exs, projb, bias, out);
}

// Round 4
// 370.250 us; speedup vs baseline: 2.7230x; 1.3228x over previous
//
#include <hip/hip_runtime.h>
#include <math.h>

// Problem constants (from reference): N=50000, E=800000, IN=256, H=4, F=64.
constexpr float SLOPE = 0.2f;

typedef __bf16 bf16x8 __attribute__((ext_vector_type(8)));
typedef float  f32x4  __attribute__((ext_vector_type(4)));

__device__ __forceinline__ int imin(int a, int b) { return a < b ? a : b; }

// ---------------------------------------------------------------------------
// Fused weight prep + degree histogram.
// Blocks [0,512): Bt[n][k] = bf16( n<256 ? W[k][n] : skw[k][n-256] ).
// Blocks [512,...): histogram of target degrees.
// ---------------------------------------------------------------------------
__global__ __launch_bounds__(256) void prep_hist(
    const float* __restrict__ W, const float* __restrict__ skw,
    __bf16* __restrict__ Bt,
    const int* __restrict__ etrg, int* __restrict__ cnt, int E)
{
    if (blockIdx.x < 512) {
        const int i = blockIdx.x * 256 + threadIdx.x;   // i = n*256 + k
        const int n = i >> 8, k = i & 255;
        const float v = (n < 256) ? W[k * 256 + n] : skw[k * 256 + (n - 256)];
        Bt[i] = (__bf16)v;
    } else {
        const int e = (blockIdx.x - 512) * 256 + threadIdx.x;
        if (e < E) atomicAdd(&cnt[etrg[e]], 1);
    }
}

// ---------------------------------------------------------------------------
// Fused MFMA GEMM: C[M,512] = bf16(x)[M,256] @ [W | skip_w].
// Cols 0..255 -> projb (bf16), cols 256..511 -> out (f32 skip values).
// 128x128 tile, BK=32, 4 waves; wave w owns rows w*32..w*32+31 (2x8 mfma tiles).
// mfma_f32_16x16x32_bf16: A[m=lane&15][k=quad*8+j], B[n=lane&15][k=quad*8+j],
// C/D: col=lane&15, row=quad*4+reg  (verified layouts, m89/m91).
// ---------------------------------------------------------------------------
__global__ __launch_bounds__(256) void gemm_mfma(
    const float* __restrict__ x, const __bf16* __restrict__ Bt,
    __bf16* __restrict__ projb, float* __restrict__ out, int M)
{
    __shared__ __bf16 As[128][40];
    __shared__ __bf16 Bs[128][40];

    const int t    = threadIdx.x;
    const int w    = t >> 6;
    const int lane = t & 63;
    const int q    = lane >> 4;
    const int ln   = lane & 15;

    const int row0 = blockIdx.x * 128;
    const int nblk = blockIdx.y;          // 0..3 -> global cols nblk*128..+127
    const int bt0  = nblk * 128;          // Bt row base (Bt row = global col)

    f32x4 acc[2][8] = {};

    for (int k0 = 0; k0 < 256; k0 += 32) {
#pragma unroll
        for (int p = 0; p < 2; ++p) {
            const int idx = p * 256 + t;
            const int r   = idx >> 2;          // 0..127
            const int ko  = (idx & 3) * 8;     // 0,8,16,24
            const int ga  = imin(row0 + r, M - 1);
            const float4 f0 = *(const float4*)(x + (size_t)ga * 256 + k0 + ko);
            const float4 f1 = *(const float4*)(x + (size_t)ga * 256 + k0 + ko + 4);
            bf16x8 av;
            av[0] = (__bf16)f0.x; av[1] = (__bf16)f0.y;
            av[2] = (__bf16)f0.z; av[3] = (__bf16)f0.w;
            av[4] = (__bf16)f1.x; av[5] = (__bf16)f1.y;
            av[6] = (__bf16)f1.z; av[7] = (__bf16)f1.w;
            *(bf16x8*)&As[r][ko] = av;
            *(bf16x8*)&Bs[r][ko] =
                *(const bf16x8*)(Bt + (size_t)(bt0 + r) * 256 + k0 + ko);
        }
        __syncthreads();

        bf16x8 af[2], bfr[8];
#pragma unroll
        for (int rb = 0; rb < 2; ++rb)
            af[rb] = *(const bf16x8*)&As[w * 32 + rb * 16 + ln][q * 8];
#pragma unroll
        for (int cb = 0; cb < 8; ++cb)
            bfr[cb] = *(const bf16x8*)&Bs[cb * 16 + ln][q * 8];
#pragma unroll
        for (int rb = 0; rb < 2; ++rb)
#pragma unroll
            for (int cb = 0; cb < 8; ++cb)
                acc[rb][cb] = __builtin_amdgcn_mfma_f32_16x16x32_bf16(
                    af[rb], bfr[cb], acc[rb][cb], 0, 0, 0);
        __syncthreads();
    }

    const bool isProj  = (nblk < 2);
    const int  colbase = (nblk & 1) * 128;
#pragma unroll
    for (int rb = 0; rb < 2; ++rb) {
#pragma unroll
        for (int r = 0; r < 4; ++r) {
            const int grow = row0 + w * 32 + rb * 16 + q * 4 + r;
            if (grow < M) {
#pragma unroll
                for (int cb = 0; cb < 8; ++cb) {
                    const float v = acc[rb][cb][r];
                    const int gcol = colbase + cb * 16 + ln;
                    if (isProj) projb[(size_t)grow * 256 + gcol] = (__bf16)v;
                    else        out[(size_t)grow * 256 + gcol]   = v;
                }
            }
        }
    }
}

// ---------------------------------------------------------------------------
// Per-node attention scores from bf16 proj: one block per node, wave h
// reduces its 64 lanes.
// ---------------------------------------------------------------------------
__global__ __launch_bounds__(256) void scores_k(
    const __bf16* __restrict__ projb,
    const float* __restrict__ a_src, const float* __restrict__ a_trg,
    float* __restrict__ s_src, float* __restrict__ s_trg)
{
    const int n = blockIdx.x;
    const int t = threadIdx.x;
    const int h = t >> 6;
    const int f = t & 63;

    const float p  = (float)projb[(size_t)n * 256 + t];
    float vs = p * a_src[h * 64 + f];
    float vt = p * a_trg[h * 64 + f];

#pragma unroll
    for (int off = 32; off > 0; off >>= 1) {
        vs += __shfl_down(vs, off);
        vt += __shfl_down(vt, off);
    }
    if (f == 0) {
        s_src[n * 4 + h] = vs;
        s_trg[n * 4 + h] = vt;
    }
}

// ---------------------------------------------------------------------------
// Hierarchical exclusive scan, phase A: block-local scan of 1024-elem chunks.
// Writes block-local exclusive prefix to off[], block total to bsum[].
// ---------------------------------------------------------------------------
__global__ __launch_bounds__(1024) void scanA(
    const int* __restrict__ cnt, int* __restrict__ off, int* __restrict__ bsum, int N)
{
    __shared__ int wsum[16];
    const int t = threadIdx.x;
    const int lane = t & 63;
    const int w = t >> 6;
    const int i = blockIdx.x * 1024 + t;
    const int v = (i < N) ? cnt[i] : 0;

    int s = v;
#pragma unroll
    for (int d = 1; d < 64; d <<= 1) {
        int o = __shfl_up(s, d);
        if (lane >= d) s += o;
    }
    if (lane == 63) wsum[w] = s;
    __syncthreads();
    if (w == 0 && lane < 16) {
        int ws = wsum[lane];
        int sc = ws;
#pragma unroll
        for (int d = 1; d < 16; d <<= 1) {
            int o = __shfl_up(sc, d);
            if (lane >= d) sc += o;
        }
        wsum[lane] = sc - ws;   // exclusive wave offset
    }
    __syncthreads();
    const int excl = wsum[w] + s - v;   // block-local exclusive
    if (i < N) off[i] = excl;
    if (t == 1023) bsum[blockIdx.x] = excl + v;  // block total
}

// ---------------------------------------------------------------------------
// Phase B: one wave scans the block totals in place (exclusive).
// ---------------------------------------------------------------------------
__global__ __launch_bounds__(64) void scanB(int* __restrict__ bsum, int nb)
{
    const int lane = threadIdx.x;
    int carry = 0;
    for (int base = 0; base < nb; base += 64) {
        const int i = base + lane;
        const int v = (i < nb) ? bsum[i] : 0;
        int s = v;
#pragma unroll
        for (int d = 1; d < 64; d <<= 1) {
            int o = __shfl_up(s, d);
            if (lane >= d) s += o;
        }
        if (i < nb) bsum[i] = carry + s - v;
        carry += __shfl(s, 63);
    }
}

// ---------------------------------------------------------------------------
// Phase C: add block offsets; produce final off[] and working copy cur[].
// ---------------------------------------------------------------------------
__global__ __launch_bounds__(256) void scanC(
    int* __restrict__ off, const int* __restrict__ bsum, int* __restrict__ cur,
    int N, int E)
{
    const int i = blockIdx.x * 256 + threadIdx.x;
    if (i < N) {
        const int o = off[i] + bsum[i >> 10];
        off[i] = o;
        cur[i] = o;
    }
    if (i == 0) off[N] = E;
}

// ---------------------------------------------------------------------------
// Scatter edge sources into target-sorted order (4 B per edge only; the
// exp weights are recomputed cheaply in the aggregate kernel).
// ---------------------------------------------------------------------------
__global__ __launch_bounds__(256) void scatter_k(
    const int* __restrict__ esrc, const int* __restrict__ etrg,
    int* __restrict__ cur, int* __restrict__ srcs, int E)
{
    const int e = blockIdx.x * 256 + threadIdx.x;
    if (e < E) {
        const int pos = atomicAdd(&cur[etrg[e]], 1);
        srcs[pos] = esrc[e];
    }
}

// ---------------------------------------------------------------------------
// Fused softmax + aggregation + skip + bias + output activation.
// One block per target node; thread t owns feature element t (h=t>>6).
// 8-way unrolled: batch the srcs loads, then issue 8 independent proj-row
// gathers + 8 score gathers concurrently (MLP ~16) before the dependent
// exp/FMA chain. Global-max shift of the reference cancels in ex/denom.
// out already contains the skip projection (gemm_mfma cols 256..511).
// ---------------------------------------------------------------------------
__global__ __launch_bounds__(256) void aggregate_csr(
    const int* __restrict__ off, const int* __restrict__ srcs,
    const float* __restrict__ s_src, const float* __restrict__ s_trg,
    const __bf16* __restrict__ projb, const float* __restrict__ bias,
    float* __restrict__ out)
{
    const int n = blockIdx.x;
    const int t = threadIdx.x;
    const int h = t >> 6;

    const float st = s_trg[n * 4 + h];
    const int b0 = off[n], b1 = off[n + 1];

    float acc = 0.f, denom = 0.f;
    int i = b0;

    while (i + 8 <= b1) {
        int s[8];
#pragma unroll
        for (int j = 0; j < 8; ++j) s[j] = srcs[i + j];
        float p[8], sv[8];
#pragma unroll
        for (int j = 0; j < 8; ++j) {
            p[j]  = (float)projb[(size_t)s[j] * 256 + t];
            sv[j] = s_src[s[j] * 4 + h];
        }
#pragma unroll
        for (int j = 0; j < 8; ++j) {
            float v = sv[j] + st;
            v = v > 0.f ? v : SLOPE * v;
            const float e = __expf(v);
            denom += e;
            acc += e * p[j];
        }
        i += 8;
    }
    if (i + 4 <= b1) {
        int s[4];
#pragma unroll
        for (int j = 0; j < 4; ++j) s[j] = srcs[i + j];
        float p[4], sv[4];
#pragma unroll
        for (int j = 0; j < 4; ++j) {
            p[j]  = (float)projb[(size_t)s[j] * 256 + t];
            sv[j] = s_src[s[j] * 4 + h];
        }
#pragma unroll
        for (int j = 0; j < 4; ++j) {
            float v = sv[j] + st;
            v = v > 0.f ? v : SLOPE * v;
            const float e = __expf(v);
            denom += e;
            acc += e * p[j];
        }
        i += 4;
    }
    while (i < b1) {
        const int s = srcs[i];
        float v = s_src[s * 4 + h] + st;
        v = v > 0.f ? v : SLOPE * v;
        const float e = __expf(v);
        denom += e;
        acc += e * (float)projb[(size_t)s * 256 + t];
        ++i;
    }

    const size_t o = (size_t)n * 256 + t;
    float val = acc / (denom + 1e-16f) + out[o] + bias[t];
    out[o] = val > 0.f ? val : SLOPE * val;
}

extern "C" void kernel_launch(void* const* d_in, const int* in_sizes, int n_in,
                              void* d_out, int out_size, void* d_ws, size_t ws_size,
                              hipStream_t stream)
{
    const float* x     = (const float*)d_in[0];
    const float* W     = (const float*)d_in[1];
    const float* a_src = (const float*)d_in[2];
    const float* a_trg = (const float*)d_in[3];
    const float* skw   = (const float*)d_in[4];
    const float* bias  = (const float*)d_in[5];
    const int*   esrc  = (const int*)d_in[6];
    const int*   etrg  = (const int*)d_in[7];

    const int N = in_sizes[0] / 256;   // 50000
    const int E = in_sizes[6];         // 800000
    float* out = (float*)d_out;

    // workspace: projb bf16[N*256] | Bt bf16[512*256] | s_src f32[N*4] |
    //            s_trg f32[N*4] | cnt[N] | off[N+1] | cur[N] | bsum[64] | srcs[E]
    __bf16* projb = (__bf16*)d_ws;
    __bf16* Bt    = projb + (size_t)N * 256;
    float*  s_src = (float*)(Bt + 512 * 256);
    float*  s_trg = s_src + (size_t)N * 4;
    int*    cnt   = (int*)(s_trg + (size_t)N * 4);
    int*    off   = cnt + N;
    int*    cur   = off + (N + 1);
    int*    bsum  = cur + N;
    int*    srcs  = bsum + 64;

    const int nb = (N + 1023) / 1024;

    hipMemsetAsync(cnt, 0, (size_t)N * sizeof(int), stream);

    prep_hist<<<512 + (E + 255) / 256, 256, 0, stream>>>(W, skw, Bt, etrg, cnt, E);

    dim3 g((N + 127) / 128, 4);
    gemm_mfma<<<g, 256, 0, stream>>>(x, Bt, projb, out, N);

    scores_k<<<N, 256, 0, stream>>>(projb, a_src, a_trg, s_src, s_trg);

    scanA<<<nb, 1024, 0, stream>>>(cnt, off, bsum, N);
    scanB<<<1, 64, 0, stream>>>(bsum, nb);
    scanC<<<(N + 255) / 256, 256, 0, stream>>>(off, bsum, cur, N, E);

    scatter_k<<<(E + 255) / 256, 256, 0, stream>>>(esrc, etrg, cur, srcs, E);

    aggregate_csr<<<N, 256, 0, stream>>>(off, srcs, s_src, s_trg, projb, bias, out);
}

// Round 5
// 340.570 us; speedup vs baseline: 2.9603x; 1.0872x over previous
//
#include <hip/hip_runtime.h>
#include <math.h>

// Problem constants (from reference): N=50000, E=800000, IN=256, H=4, F=64.
constexpr float SLOPE = 0.2f;

typedef __bf16 bf16x8 __attribute__((ext_vector_type(8)));
typedef __bf16 bf16x4 __attribute__((ext_vector_type(4)));
typedef float  f32x4  __attribute__((ext_vector_type(4)));

__device__ __forceinline__ int imin(int a, int b) { return a < b ? a : b; }

// Async global->LDS 16B copy. HW semantics: LDS dest = wave-uniform base +
// lane*16 (per-lane pointer's first-lane value is used as base). Our staging
// index order matches lane order exactly, so layouts coincide.
__device__ __forceinline__ void glds16(const void* g, void* l) {
    __builtin_amdgcn_global_load_lds(
        (const __attribute__((address_space(1))) unsigned int*)g,
        (__attribute__((address_space(3))) unsigned int*)l,
        16, 0, 0);
}

// ---------------------------------------------------------------------------
// Fused prep: [0,512) Bt transpose+cast | [512,512+nxb) x->bf16 cast |
// rest: target-degree histogram.
// ---------------------------------------------------------------------------
__global__ __launch_bounds__(256) void prep_k(
    const float* __restrict__ W, const float* __restrict__ skw,
    __bf16* __restrict__ Bt,
    const float* __restrict__ x, __bf16* __restrict__ xb, int nxv, int nxb,
    const int* __restrict__ etrg, int* __restrict__ cnt, int E)
{
    const int b = blockIdx.x;
    if (b < 512) {
        const int i = b * 256 + threadIdx.x;     // i = n*256 + k
        const int n = i >> 8, k = i & 255;
        const float v = (n < 256) ? W[k * 256 + n] : skw[k * 256 + (n - 256)];
        Bt[i] = (__bf16)v;
    } else if (b < 512 + nxb) {
        const int gid = (b - 512) * 256 + threadIdx.x;   // 8 f32 per thread
        if (gid < nxv) {
            const float4 f0 = *(const float4*)(x + (size_t)gid * 8);
            const float4 f1 = *(const float4*)(x + (size_t)gid * 8 + 4);
            bf16x8 v;
            v[0] = (__bf16)f0.x; v[1] = (__bf16)f0.y;
            v[2] = (__bf16)f0.z; v[3] = (__bf16)f0.w;
            v[4] = (__bf16)f1.x; v[5] = (__bf16)f1.y;
            v[6] = (__bf16)f1.z; v[7] = (__bf16)f1.w;
            *(bf16x8*)(xb + (size_t)gid * 8) = v;
        }
    } else {
        const int e = (b - 512 - nxb) * 256 + threadIdx.x;
        if (e < E) atomicAdd(&cnt[etrg[e]], 1);
    }
}

// ---------------------------------------------------------------------------
// MFMA GEMM via global_load_lds: C[M,512] = xb[M,256] @ [W | skip_w].
// Cols 0..255 -> projb (bf16), 256..511 -> out (f32 skip values).
// 128x128 tile, BK=32, 4 waves, 2x8 16x16x32 mfma per wave.
// A/B frag: [m|n]=lane&15, k=quad*8+j; C/D: col=lane&15, row=quad*4+reg
// (verified m89/m91). LDS tiles row-contiguous 128x32 bf16 (64 B rows, no
// padding — required by glds; m97 precedent says conflicts are acceptable).
// ---------------------------------------------------------------------------
__global__ __launch_bounds__(256) void gemm_mfma(
    const __bf16* __restrict__ xb, const __bf16* __restrict__ Bt,
    __bf16* __restrict__ projb, float* __restrict__ out, int M)
{
    __shared__ __bf16 As[128 * 32];
    __shared__ __bf16 Bs[128 * 32];

    const int t    = threadIdx.x;
    const int w    = t >> 6;
    const int lane = t & 63;
    const int q    = lane >> 4;
    const int ln   = lane & 15;

    const int row0 = blockIdx.x * 128;
    const int bt0  = blockIdx.y * 128;     // Bt row base (Bt row = global col)

    f32x4 acc[2][8] = {};

    for (int k0 = 0; k0 < 256; k0 += 32) {
#pragma unroll
        for (int p = 0; p < 2; ++p) {
            const int idx = p * 256 + t;
            const int r   = idx >> 2;          // 0..127
            const int ko  = (idx & 3) * 8;     // 0,8,16,24
            const int ga  = imin(row0 + r, M - 1);
            glds16(xb + (size_t)ga * 256 + k0 + ko, &As[idx * 8]);
            glds16(Bt + (size_t)(bt0 + r) * 256 + k0 + ko, &Bs[idx * 8]);
        }
        asm volatile("s_waitcnt vmcnt(0)" ::: "memory");
        __syncthreads();

        bf16x8 af[2], bfr[8];
#pragma unroll
        for (int rb = 0; rb < 2; ++rb)
            af[rb] = *(const bf16x8*)&As[(w * 32 + rb * 16 + ln) * 32 + q * 8];
#pragma unroll
        for (int cb = 0; cb < 8; ++cb)
            bfr[cb] = *(const bf16x8*)&Bs[(cb * 16 + ln) * 32 + q * 8];
#pragma unroll
        for (int rb = 0; rb < 2; ++rb)
#pragma unroll
            for (int cb = 0; cb < 8; ++cb)
                acc[rb][cb] = __builtin_amdgcn_mfma_f32_16x16x32_bf16(
                    af[rb], bfr[cb], acc[rb][cb], 0, 0, 0);
        __syncthreads();
    }

    const bool isProj  = (blockIdx.y < 2);
    const int  colbase = (blockIdx.y & 1) * 128;
#pragma unroll
    for (int rb = 0; rb < 2; ++rb) {
#pragma unroll
        for (int r = 0; r < 4; ++r) {
            const int grow = row0 + w * 32 + rb * 16 + q * 4 + r;
            if (grow < M) {
#pragma unroll
                for (int cb = 0; cb < 8; ++cb) {
                    const float v = acc[rb][cb][r];
                    const int gcol = colbase + cb * 16 + ln;
                    if (isProj) projb[(size_t)grow * 256 + gcol] = (__bf16)v;
                    else        out[(size_t)grow * 256 + gcol]   = v;
                }
            }
        }
    }
}

// ---------------------------------------------------------------------------
// Scores: one wave per node, 4 bf16 (8 B) per lane, width-16 shuffle reduce
// (head h owns lanes 16h..16h+15 since 4 consecutive elems never straddle a
// head boundary).
// ---------------------------------------------------------------------------
__global__ __launch_bounds__(256) void scores_k(
    const __bf16* __restrict__ projb,
    const float* __restrict__ a_src, const float* __restrict__ a_trg,
    float* __restrict__ s_src, float* __restrict__ s_trg, int N)
{
    const int nid  = blockIdx.x * 4 + (threadIdx.x >> 6);
    const int lane = threadIdx.x & 63;
    if (nid >= N) return;

    const bf16x4 p4  = *(const bf16x4*)(projb + (size_t)nid * 256 + lane * 4);
    const float4 as4 = *(const float4*)(a_src + lane * 4);
    const float4 at4 = *(const float4*)(a_trg + lane * 4);

    float vs = (float)p4[0] * as4.x + (float)p4[1] * as4.y +
               (float)p4[2] * as4.z + (float)p4[3] * as4.w;
    float vt = (float)p4[0] * at4.x + (float)p4[1] * at4.y +
               (float)p4[2] * at4.z + (float)p4[3] * at4.w;

#pragma unroll
    for (int d = 8; d > 0; d >>= 1) {
        vs += __shfl_down(vs, d, 16);
        vt += __shfl_down(vt, d, 16);
    }
    if ((lane & 15) == 0) {
        s_src[nid * 4 + (lane >> 4)] = vs;
        s_trg[nid * 4 + (lane >> 4)] = vt;
    }
}

// ---------------------------------------------------------------------------
// Scan phase A: block-local exclusive scan of 1024-elem chunks.
// ---------------------------------------------------------------------------
__global__ __launch_bounds__(1024) void scanA(
    const int* __restrict__ cnt, int* __restrict__ off, int* __restrict__ bsum, int N)
{
    __shared__ int wsum[16];
    const int t = threadIdx.x;
    const int lane = t & 63;
    const int w = t >> 6;
    const int i = blockIdx.x * 1024 + t;
    const int v = (i < N) ? cnt[i] : 0;

    int s = v;
#pragma unroll
    for (int d = 1; d < 64; d <<= 1) {
        int o = __shfl_up(s, d);
        if (lane >= d) s += o;
    }
    if (lane == 63) wsum[w] = s;
    __syncthreads();
    if (w == 0 && lane < 16) {
        int ws = wsum[lane];
        int sc = ws;
#pragma unroll
        for (int d = 1; d < 16; d <<= 1) {
            int o = __shfl_up(sc, d);
            if (lane >= d) sc += o;
        }
        wsum[lane] = sc - ws;
    }
    __syncthreads();
    const int excl = wsum[w] + s - v;
    if (i < N) off[i] = excl;
    if (t == 1023) bsum[blockIdx.x] = excl + v;
}

// ---------------------------------------------------------------------------
// Scan phase BC fused: each block directly sums the <=49 preceding block
// totals (wave butterfly), adds, writes final off[] and working copy cur[].
// ---------------------------------------------------------------------------
__global__ __launch_bounds__(256) void scanBC(
    int* __restrict__ off, const int* __restrict__ bsum, int* __restrict__ cur,
    int N, int E)
{
    const int i = blockIdx.x * 256 + threadIdx.x;
    const int chunk = blockIdx.x >> 2;          // which 1024-chunk this block is in
    const int lane = threadIdx.x & 63;

    int v = (lane < chunk) ? bsum[lane] : 0;
#pragma unroll
    for (int d = 1; d < 64; d <<= 1) v += __shfl_xor(v, d);

    if (i < N) {
        const int o = off[i] + v;
        off[i] = o;
        cur[i] = o;
    }
    if (i == 0) off[N] = E;
}

// ---------------------------------------------------------------------------
// Scatter: target-sorted srcs + precomputed per-(edge,head) exp weights.
// Global-max shift of the reference cancels in ex/denom; scores are O(10)
// so f32 exp is safe.
// ---------------------------------------------------------------------------
__global__ __launch_bounds__(256) void scatter_k(
    const int* __restrict__ esrc, const int* __restrict__ etrg,
    int* __restrict__ cur,
    const float* __restrict__ s_src, const float* __restrict__ s_trg,
    int* __restrict__ srcs, float* __restrict__ exs, int E)
{
    const int e = blockIdx.x * 256 + threadIdx.x;
    if (e >= E) return;
    const int s  = esrc[e];
    const int tg = etrg[e];
    const int pos = atomicAdd(&cur[tg], 1);
    srcs[pos] = s;
    const float4 ss = *(const float4*)(s_src + (size_t)s * 4);
    const float4 st = *(const float4*)(s_trg + (size_t)tg * 4);
    float4 ex; float v;
    v = ss.x + st.x; v = v > 0.f ? v : SLOPE * v; ex.x = __expf(v);
    v = ss.y + st.y; v = v > 0.f ? v : SLOPE * v; ex.y = __expf(v);
    v = ss.z + st.z; v = v > 0.f ? v : SLOPE * v; ex.z = __expf(v);
    v = ss.w + st.w; v = v > 0.f ? v : SLOPE * v; ex.w = __expf(v);
    *(float4*)(exs + (size_t)pos * 4) = ex;
}

// ---------------------------------------------------------------------------
// Fused softmax + aggregation + skip + bias + activation.
// One block per target; thread t owns feature elem t (h=t>>6). MLP-8 batch:
// 8 srcs (consecutive), 8 exp weights (broadcast, imm-offset), 8 independent
// projb row gathers (32-bit saddr+voffset addressing).
// out already holds the skip projection (gemm cols 256..511).
// ---------------------------------------------------------------------------
__global__ __launch_bounds__(256) void aggregate_csr(
    const int* __restrict__ off, const int* __restrict__ srcs,
    const float* __restrict__ exs, const __bf16* __restrict__ projb,
    const float* __restrict__ bias, float* __restrict__ out)
{
    const int n = blockIdx.x;
    const int t = threadIdx.x;
    const int h = t >> 6;

    const int b0 = off[n], b1 = off[n + 1];

    float acc = 0.f, denom = 0.f;
    int i = b0;
    for (; i + 8 <= b1; i += 8) {
        int s[8];
#pragma unroll
        for (int j = 0; j < 8; ++j) s[j] = srcs[i + j];
        float p[8];
#pragma unroll
        for (int j = 0; j < 8; ++j)
            p[j] = (float)projb[(unsigned)s[j] * 256u + t];
        const float* ep = exs + (size_t)i * 4 + h;
        float e[8];
#pragma unroll
        for (int j = 0; j < 8; ++j) e[j] = ep[j * 4];
#pragma unroll
        for (int j = 0; j < 8; ++j) { denom += e[j]; acc += e[j] * p[j]; }
    }
    for (; i < b1; ++i) {
        const int s = srcs[i];
        const float e = exs[(size_t)i * 4 + h];
        denom += e;
        acc += e * (float)projb[(unsigned)s * 256u + t];
    }

    const size_t o = (size_t)n * 256 + t;
    float val = acc / (denom + 1e-16f) + out[o] + bias[t];
    out[o] = val > 0.f ? val : SLOPE * val;
}

extern "C" void kernel_launch(void* const* d_in, const int* in_sizes, int n_in,
                              void* d_out, int out_size, void* d_ws, size_t ws_size,
                              hipStream_t stream)
{
    const float* x     = (const float*)d_in[0];
    const float* W     = (const float*)d_in[1];
    const float* a_src = (const float*)d_in[2];
    const float* a_trg = (const float*)d_in[3];
    const float* skw   = (const float*)d_in[4];
    const float* bias  = (const float*)d_in[5];
    const int*   esrc  = (const int*)d_in[6];
    const int*   etrg  = (const int*)d_in[7];

    const int N = in_sizes[0] / 256;   // 50000
    const int E = in_sizes[6];         // 800000
    float* out = (float*)d_out;

    // workspace: projb bf16[N*256] | Bt bf16[512*256] | xb bf16[N*256]
    //            (exs f32[4E] OVERLAYS xb — xb is dead after gemm_mfma) |
    //            s_src f32[4N] | s_trg f32[4N] | cnt[N] | off[N+1] | cur[N] |
    //            bsum[64] | srcs[E]
    __bf16* projb = (__bf16*)d_ws;
    __bf16* Bt    = projb + (size_t)N * 256;
    __bf16* xb    = Bt + 512 * 256;
    float*  exs   = (float*)xb;                       // overlay (see above)
    float*  s_src = (float*)(xb + (size_t)N * 256);
    float*  s_trg = s_src + (size_t)N * 4;
    int*    cnt   = (int*)(s_trg + (size_t)N * 4);
    int*    off   = cnt + N;
    int*    cur   = off + (N + 1);
    int*    bsum  = cur + N;
    int*    srcs  = bsum + 64;

    const int nxv = (N * 256) / 8;                    // bf16x8 vectors in x
    const int nxb = (nxv + 255) / 256;
    const int nhb = (E + 255) / 256;
    const int nsc = (N + 1023) / 1024;

    hipMemsetAsync(cnt, 0, (size_t)N * sizeof(int), stream);

    prep_k<<<512 + nxb + nhb, 256, 0, stream>>>(W, skw, Bt, x, xb, nxv, nxb,
                                                etrg, cnt, E);

    dim3 g((N + 127) / 128, 4);
    gemm_mfma<<<g, 256, 0, stream>>>(xb, Bt, projb, out, N);

    scores_k<<<(N + 3) / 4, 256, 0, stream>>>(projb, a_src, a_trg, s_src, s_trg, N);

    scanA<<<nsc, 1024, 0, stream>>>(cnt, off, bsum, N);
    scanBC<<<(N + 255) / 256, 256, 0, stream>>>(off, bsum, cur, N, E);

    scatter_k<<<(E + 255) / 256, 256, 0, stream>>>(esrc, etrg, cur, s_src, s_trg,
                                                   srcs, exs, E);

    aggregate_csr<<<N, 256, 0, stream>>>(off, srcs, exs, projb, bias, out);
}

// Round 6
// 309.506 us; speedup vs baseline: 3.2574x; 1.1004x over previous
//
#include <hip/hip_runtime.h>
#include <math.h>

// Problem constants (from reference): N=50000, E=800000, IN=256, H=4, F=64.
constexpr float SLOPE = 0.2f;

typedef __bf16 bf16x8 __attribute__((ext_vector_type(8)));
typedef __bf16 bf16x4 __attribute__((ext_vector_type(4)));
typedef float  f32x4  __attribute__((ext_vector_type(4)));

__device__ __forceinline__ int imin(int a, int b) { return a < b ? a : b; }

// Async global->LDS 16B copy. LDS dest must be lane-linear (wave-uniform base
// + lane*16) — our staging index order matches lane order exactly.
__device__ __forceinline__ void glds16(const void* g, void* l) {
    __builtin_amdgcn_global_load_lds(
        (const __attribute__((address_space(1))) unsigned int*)g,
        (__attribute__((address_space(3))) unsigned int*)l,
        16, 0, 0);
}

// ---------------------------------------------------------------------------
// Fused prep: [0,512) Bt transpose+cast | [512,512+nxb) x->bf16 cast |
// rest: target-degree histogram.
// ---------------------------------------------------------------------------
__global__ __launch_bounds__(256) void prep_k(
    const float* __restrict__ W, const float* __restrict__ skw,
    __bf16* __restrict__ Bt,
    const float* __restrict__ x, __bf16* __restrict__ xb, int nxv, int nxb,
    const int* __restrict__ etrg, int* __restrict__ cnt, int E)
{
    const int b = blockIdx.x;
    if (b < 512) {
        const int i = b * 256 + threadIdx.x;     // i = n*256 + k
        const int n = i >> 8, k = i & 255;
        const float v = (n < 256) ? W[k * 256 + n] : skw[k * 256 + (n - 256)];
        Bt[i] = (__bf16)v;
    } else if (b < 512 + nxb) {
        const int gid = (b - 512) * 256 + threadIdx.x;   // 8 f32 per thread
        if (gid < nxv) {
            const float4 f0 = *(const float4*)(x + (size_t)gid * 8);
            const float4 f1 = *(const float4*)(x + (size_t)gid * 8 + 4);
            bf16x8 v;
            v[0] = (__bf16)f0.x; v[1] = (__bf16)f0.y;
            v[2] = (__bf16)f0.z; v[3] = (__bf16)f0.w;
            v[4] = (__bf16)f1.x; v[5] = (__bf16)f1.y;
            v[6] = (__bf16)f1.z; v[7] = (__bf16)f1.w;
            *(bf16x8*)(xb + (size_t)gid * 8) = v;
        }
    } else {
        const int e = (b - 512 - nxb) * 256 + threadIdx.x;
        if (e < E) atomicAdd(&cnt[etrg[e]], 1);
    }
}

// ---------------------------------------------------------------------------
// MFMA GEMM, 256x128 tile: C[M,512] = xb[M,256] @ [W | skip_w].
// y=0,1 -> projb bf16 cols 0..255; y=2,3 -> out f32 (skip) cols 256..511.
// BK=32, 4 waves; wave owns 64 rows (4 rb x 8 cb 16x16x32 mfma -> 32 MFMA
// per 12 LDS frag reads per lane, 2x better MFMA:LDS ratio than 128-tile).
// A/B frag: [m|n]=lane&15, k=quad*8+j; C/D: col=lane&15, row=quad*4+reg.
// ---------------------------------------------------------------------------
__global__ __launch_bounds__(256, 2) void gemm_mfma(
    const __bf16* __restrict__ xb, const __bf16* __restrict__ Bt,
    __bf16* __restrict__ projb, float* __restrict__ out, int M)
{
    __shared__ __bf16 As[256 * 32];   // 16 KB
    __shared__ __bf16 Bs[128 * 32];   //  8 KB

    const int t    = threadIdx.x;
    const int w    = t >> 6;
    const int lane = t & 63;
    const int q    = lane >> 4;
    const int ln   = lane & 15;

    const int row0 = blockIdx.x * 256;
    const int bt0  = blockIdx.y * 128;     // Bt row base (Bt row = global col)

    f32x4 acc[4][8] = {};

    for (int k0 = 0; k0 < 256; k0 += 32) {
#pragma unroll
        for (int p = 0; p < 4; ++p) {          // A: 256 rows x 32 k
            const int idx = p * 256 + t;
            const int r   = idx >> 2;          // 0..255
            const int ko  = (idx & 3) * 8;     // 0,8,16,24
            const int ga  = imin(row0 + r, M - 1);
            glds16(xb + (size_t)ga * 256 + k0 + ko, &As[idx * 8]);
        }
#pragma unroll
        for (int p = 0; p < 2; ++p) {          // B: 128 rows x 32 k
            const int idx = p * 256 + t;
            const int r   = idx >> 2;          // 0..127
            const int ko  = (idx & 3) * 8;
            glds16(Bt + (size_t)(bt0 + r) * 256 + k0 + ko, &Bs[idx * 8]);
        }
        asm volatile("s_waitcnt vmcnt(0)" ::: "memory");
        __syncthreads();

        bf16x8 af[4], bfr[8];
#pragma unroll
        for (int rb = 0; rb < 4; ++rb)
            af[rb] = *(const bf16x8*)&As[(w * 64 + rb * 16 + ln) * 32 + q * 8];
#pragma unroll
        for (int cb = 0; cb < 8; ++cb)
            bfr[cb] = *(const bf16x8*)&Bs[(cb * 16 + ln) * 32 + q * 8];
#pragma unroll
        for (int rb = 0; rb < 4; ++rb)
#pragma unroll
            for (int cb = 0; cb < 8; ++cb)
                acc[rb][cb] = __builtin_amdgcn_mfma_f32_16x16x32_bf16(
                    af[rb], bfr[cb], acc[rb][cb], 0, 0, 0);
        __syncthreads();
    }

    const bool isProj  = (blockIdx.y < 2);
    const int  colbase = (blockIdx.y & 1) * 128;
#pragma unroll
    for (int rb = 0; rb < 4; ++rb) {
#pragma unroll
        for (int r = 0; r < 4; ++r) {
            const int grow = row0 + w * 64 + rb * 16 + q * 4 + r;
            if (grow < M) {
#pragma unroll
                for (int cb = 0; cb < 8; ++cb) {
                    const float v = acc[rb][cb][r];
                    const int gcol = colbase + cb * 16 + ln;
                    if (isProj) projb[(size_t)grow * 256 + gcol] = (__bf16)v;
                    else        out[(size_t)grow * 256 + gcol]   = v;
                }
            }
        }
    }
}

// ---------------------------------------------------------------------------
// Scores: one wave per node, 4 bf16 (8 B) per lane, width-16 shuffle reduce.
// ---------------------------------------------------------------------------
__global__ __launch_bounds__(256) void scores_k(
    const __bf16* __restrict__ projb,
    const float* __restrict__ a_src, const float* __restrict__ a_trg,
    float* __restrict__ s_src, float* __restrict__ s_trg, int N)
{
    const int nid  = blockIdx.x * 4 + (threadIdx.x >> 6);
    const int lane = threadIdx.x & 63;
    if (nid >= N) return;

    const bf16x4 p4  = *(const bf16x4*)(projb + (size_t)nid * 256 + lane * 4);
    const float4 as4 = *(const float4*)(a_src + lane * 4);
    const float4 at4 = *(const float4*)(a_trg + lane * 4);

    float vs = (float)p4[0] * as4.x + (float)p4[1] * as4.y +
               (float)p4[2] * as4.z + (float)p4[3] * as4.w;
    float vt = (float)p4[0] * at4.x + (float)p4[1] * at4.y +
               (float)p4[2] * at4.z + (float)p4[3] * at4.w;

#pragma unroll
    for (int d = 8; d > 0; d >>= 1) {
        vs += __shfl_down(vs, d, 16);
        vt += __shfl_down(vt, d, 16);
    }
    if ((lane & 15) == 0) {
        s_src[nid * 4 + (lane >> 4)] = vs;
        s_trg[nid * 4 + (lane >> 4)] = vt;
    }
}

// ---------------------------------------------------------------------------
// Scan phase A: block-local exclusive scan of 1024-elem chunks.
// ---------------------------------------------------------------------------
__global__ __launch_bounds__(1024) void scanA(
    const int* __restrict__ cnt, int* __restrict__ off, int* __restrict__ bsum, int N)
{
    __shared__ int wsum[16];
    const int t = threadIdx.x;
    const int lane = t & 63;
    const int w = t >> 6;
    const int i = blockIdx.x * 1024 + t;
    const int v = (i < N) ? cnt[i] : 0;

    int s = v;
#pragma unroll
    for (int d = 1; d < 64; d <<= 1) {
        int o = __shfl_up(s, d);
        if (lane >= d) s += o;
    }
    if (lane == 63) wsum[w] = s;
    __syncthreads();
    if (w == 0 && lane < 16) {
        int ws = wsum[lane];
        int sc = ws;
#pragma unroll
        for (int d = 1; d < 16; d <<= 1) {
            int o = __shfl_up(sc, d);
            if (lane >= d) sc += o;
        }
        wsum[lane] = sc - ws;
    }
    __syncthreads();
    const int excl = wsum[w] + s - v;
    if (i < N) off[i] = excl;
    if (t == 1023) bsum[blockIdx.x] = excl + v;
}

// ---------------------------------------------------------------------------
// Scan phase BC fused: each block sums its <=49 preceding chunk totals.
// ---------------------------------------------------------------------------
__global__ __launch_bounds__(256) void scanBC(
    int* __restrict__ off, const int* __restrict__ bsum, int* __restrict__ cur,
    int N, int E)
{
    const int i = blockIdx.x * 256 + threadIdx.x;
    const int chunk = blockIdx.x >> 2;
    const int lane = threadIdx.x & 63;

    int v = (lane < chunk) ? bsum[lane] : 0;
#pragma unroll
    for (int d = 1; d < 64; d <<= 1) v += __shfl_xor(v, d);

    if (i < N) {
        const int o = off[i] + v;
        off[i] = o;
        cur[i] = o;
    }
    if (i == 0) off[N] = E;
}

// ---------------------------------------------------------------------------
// Scatter: target-sorted srcs only (4 B/edge — exp weights are computed
// in-aggregate via lane-split + shuffle, no exs array).
// ---------------------------------------------------------------------------
__global__ __launch_bounds__(256) void scatter_k(
    const int* __restrict__ esrc, const int* __restrict__ etrg,
    int* __restrict__ cur, int* __restrict__ srcs, int E)
{
    const int e = blockIdx.x * 256 + threadIdx.x;
    if (e < E) {
        const int pos = atomicAdd(&cur[etrg[e]], 1);
        srcs[pos] = esrc[e];
    }
}

// ---------------------------------------------------------------------------
// Fused softmax + aggregation + skip + bias + activation.
// ONE WAVE per target node (4 nodes/block). Lane l owns feature elems
// 4l..4l+3 (bf16x4 = 8 B gather/lane -> one 512 B coalesced load per edge
// per wave), head h = l>>4. Per 8-edge batch, lane (h*16+j) computes the
// exp for (edge j, head h) once; values distributed via __shfl (source lane
// (l&48)|j). Global-max shift of the reference cancels in ex/denom.
// out already holds the skip projection (gemm y=2,3).
// ---------------------------------------------------------------------------
__global__ __launch_bounds__(256) void aggregate_wave(
    const int* __restrict__ off, const int* __restrict__ srcs,
    const float* __restrict__ s_src, const float* __restrict__ s_trg,
    const __bf16* __restrict__ projb, const float* __restrict__ bias,
    float* __restrict__ out, int N)
{
    const int w = threadIdx.x >> 6;
    const int l = threadIdx.x & 63;
    const int n = blockIdx.x * 4 + w;
    if (n >= N) return;

    const int h  = l >> 4;
    const int je = l & 7;
    const float st = s_trg[n * 4 + h];
    const int b0 = off[n], b1 = off[n + 1];

    f32x4 acc = {0.f, 0.f, 0.f, 0.f};
    float denom = 0.f;

    int i = b0;
    for (; i + 8 <= b1; i += 8) {
        // lane's exp assignment: edge je, head h
        const int s0 = srcs[i + je];
        float v = s_src[s0 * 4 + h] + st;
        v = v > 0.f ? v : SLOPE * v;
        const float ex = __expf(v);

        // all 8 edge ids (lane j holds srcs[i+j])
        int s[8];
#pragma unroll
        for (int j = 0; j < 8; ++j) s[j] = __shfl(s0, j);

        // 8 independent 8 B row-gathers in flight
        bf16x4 p[8];
#pragma unroll
        for (int j = 0; j < 8; ++j)
            p[j] = *(const bf16x4*)(projb + (size_t)((unsigned)s[j] * 256u) + l * 4);

        // distribute exp weights: e[j] for this lane's head from lane (l&48)|j
        float e[8];
#pragma unroll
        for (int j = 0; j < 8; ++j) e[j] = __shfl(ex, (l & 48) | j);

#pragma unroll
        for (int j = 0; j < 8; ++j) {
            denom += e[j];
            acc[0] += e[j] * (float)p[j][0];
            acc[1] += e[j] * (float)p[j][1];
            acc[2] += e[j] * (float)p[j][2];
            acc[3] += e[j] * (float)p[j][3];
        }
    }
    for (; i < b1; ++i) {
        const int s = srcs[i];
        float v = s_src[s * 4 + h] + st;
        v = v > 0.f ? v : SLOPE * v;
        const float ex = __expf(v);
        denom += ex;
        const bf16x4 p = *(const bf16x4*)(projb + (size_t)((unsigned)s * 256u) + l * 4);
        acc[0] += ex * (float)p[0];
        acc[1] += ex * (float)p[1];
        acc[2] += ex * (float)p[2];
        acc[3] += ex * (float)p[3];
    }

    const size_t o = (size_t)n * 256 + l * 4;
    const float4 sk = *(const float4*)(out + o);
    const float4 b4 = *(const float4*)(bias + l * 4);
    const float inv = 1.f / (denom + 1e-16f);
    float4 r;
    r.x = acc[0] * inv + sk.x + b4.x;
    r.y = acc[1] * inv + sk.y + b4.y;
    r.z = acc[2] * inv + sk.z + b4.z;
    r.w = acc[3] * inv + sk.w + b4.w;
    r.x = r.x > 0.f ? r.x : SLOPE * r.x;
    r.y = r.y > 0.f ? r.y : SLOPE * r.y;
    r.z = r.z > 0.f ? r.z : SLOPE * r.z;
    r.w = r.w > 0.f ? r.w : SLOPE * r.w;
    *(float4*)(out + o) = r;
}

extern "C" void kernel_launch(void* const* d_in, const int* in_sizes, int n_in,
                              void* d_out, int out_size, void* d_ws, size_t ws_size,
                              hipStream_t stream)
{
    const float* x     = (const float*)d_in[0];
    const float* W     = (const float*)d_in[1];
    const float* a_src = (const float*)d_in[2];
    const float* a_trg = (const float*)d_in[3];
    const float* skw   = (const float*)d_in[4];
    const float* bias  = (const float*)d_in[5];
    const int*   esrc  = (const int*)d_in[6];
    const int*   etrg  = (const int*)d_in[7];

    const int N = in_sizes[0] / 256;   // 50000
    const int E = in_sizes[6];         // 800000
    float* out = (float*)d_out;

    // workspace: projb bf16[N*256] | Bt bf16[512*256] | xb bf16[N*256] |
    //            s_src f32[4N] | s_trg f32[4N] | cnt[N] | off[N+1] | cur[N] |
    //            bsum[64] | srcs[E]
    __bf16* projb = (__bf16*)d_ws;
    __bf16* Bt    = projb + (size_t)N * 256;
    __bf16* xb    = Bt + 512 * 256;
    float*  s_src = (float*)(xb + (size_t)N * 256);
    float*  s_trg = s_src + (size_t)N * 4;
    int*    cnt   = (int*)(s_trg + (size_t)N * 4);
    int*    off   = cnt + N;
    int*    cur   = off + (N + 1);
    int*    bsum  = cur + N;
    int*    srcs  = bsum + 64;

    const int nxv = (N * 256) / 8;
    const int nxb = (nxv + 255) / 256;
    const int nhb = (E + 255) / 256;
    const int nsc = (N + 1023) / 1024;

    hipMemsetAsync(cnt, 0, (size_t)N * sizeof(int), stream);

    prep_k<<<512 + nxb + nhb, 256, 0, stream>>>(W, skw, Bt, x, xb, nxv, nxb,
                                                etrg, cnt, E);

    dim3 g((N + 255) / 256, 4);
    gemm_mfma<<<g, 256, 0, stream>>>(xb, Bt, projb, out, N);

    scores_k<<<(N + 3) / 4, 256, 0, stream>>>(projb, a_src, a_trg, s_src, s_trg, N);

    scanA<<<nsc, 1024, 0, stream>>>(cnt, off, bsum, N);
    scanBC<<<(N + 255) / 256, 256, 0, stream>>>(off, bsum, cur, N, E);

    scatter_k<<<(E + 255) / 256, 256, 0, stream>>>(esrc, etrg, cur, srcs, E);

    aggregate_wave<<<(N + 3) / 4, 256, 0, stream>>>(off, srcs, s_src, s_trg,
                                                    projb, bias, out, N);
}